// Round 1
// baseline (1344.973 us; speedup 1.0000x reference)
//
#include <hip/hip_runtime.h>
#include <hip/hip_bf16.h>
#include <math.h>

#define L      16384
#define CIN    200
#define CE     50
#define NS     4
#define KCL    256
#define WIN    64
#define NKEY   192

// ---------------------------------------------------------------------------
// conv3x3 reflect-pad -> x_embed (N, L, 50)
// grid (2 oc-halves, 64 tiles, N), block 256 (16x16 pixel tile)
// ---------------------------------------------------------------------------
__global__ __launch_bounds__(256) void k_conv3(const float* __restrict__ in,
                                               const float* __restrict__ Wx,
                                               float* __restrict__ xe) {
  const int ocHalf = blockIdx.x;
  const int tile   = blockIdx.y;
  const int n      = blockIdx.z;
  const int th = tile >> 3, tw = tile & 7;
  const int ty = threadIdx.x >> 4, tx = threadIdx.x & 15;
  const int oc0 = ocHalf * 25;

  __shared__ __align__(16) float patch[18][20];
  __shared__ __align__(16) float wt[25][12];

  float acc[25];
#pragma unroll
  for (int o = 0; o < 25; ++o) acc[o] = 0.f;

  const float* inN = in + (size_t)n * CIN * L;

  for (int ic = 0; ic < CIN; ++ic) {
    for (int idx = threadIdx.x; idx < 18 * 18; idx += 256) {
      int r = idx / 18, c = idx % 18;
      int gh = th * 16 + r - 1, gw = tw * 16 + c - 1;
      gh = gh < 0 ? -gh : (gh > 127 ? 254 - gh : gh);
      gw = gw < 0 ? -gw : (gw > 127 ? 254 - gw : gw);
      patch[r][c] = inN[(size_t)ic * L + gh * 128 + gw];
    }
    for (int idx = threadIdx.x; idx < 225; idx += 256) {
      int o = idx / 9, q = idx % 9;
      wt[o][q] = Wx[((size_t)(oc0 + o) * CIN + ic) * 9 + q];
    }
    __syncthreads();
    float p0 = patch[ty][tx],     p1 = patch[ty][tx + 1],     p2 = patch[ty][tx + 2];
    float p3 = patch[ty + 1][tx], p4 = patch[ty + 1][tx + 1], p5 = patch[ty + 1][tx + 2];
    float p6 = patch[ty + 2][tx], p7 = patch[ty + 2][tx + 1], p8 = patch[ty + 2][tx + 2];
#pragma unroll
    for (int o = 0; o < 25; ++o) {
      float4 w0 = *(const float4*)&wt[o][0];
      float4 w1 = *(const float4*)&wt[o][4];
      float  w8 = wt[o][8];
      acc[o] += w0.x * p0 + w0.y * p1 + w0.z * p2 + w0.w * p3 + w1.x * p4
              + w1.y * p5 + w1.z * p6 + w1.w * p7 + w8 * p8;
    }
    __syncthreads();
  }
  const int l = (th * 16 + ty) * 128 + (tw * 16 + tx);
  float* xrow = xe + ((size_t)n * L + l) * CE + oc0;
#pragma unroll
  for (int o = 0; o < 25; ++o) xrow[o] = acc[o];
}

// ---------------------------------------------------------------------------
// 1x1 Wy -> y_embed (N, L, 200).  grid (256 l-tiles, N), block 256
// ---------------------------------------------------------------------------
__global__ __launch_bounds__(256) void k_wy(const float* __restrict__ in,
                                            const float* __restrict__ Wy,
                                            float* __restrict__ ye) {
  const int n  = blockIdx.y;
  const int l0 = blockIdx.x * 64;
  __shared__ __align__(16) float At[20][64];
  __shared__ __align__(16) float Wt[20][208];
  const int pg = threadIdx.x >> 4, og = threadIdx.x & 15;

  float acc[4][13];
#pragma unroll
  for (int p = 0; p < 4; ++p)
#pragma unroll
    for (int j = 0; j < 13; ++j) acc[p][j] = 0.f;

  // zero the oc padding columns once
  for (int idx = threadIdx.x; idx < 20 * 8; idx += 256)
    Wt[idx >> 3][200 + (idx & 7)] = 0.f;

  const float* inN = in + (size_t)n * CIN * L + l0;
  for (int c0 = 0; c0 < CIN; c0 += 20) {
    __syncthreads();
    for (int idx = threadIdx.x; idx < 20 * 64; idx += 256) {
      int k = idx >> 6, p = idx & 63;
      At[k][p] = inN[(size_t)(c0 + k) * L + p];
    }
    for (int idx = threadIdx.x; idx < 200 * 20; idx += 256) {
      int oc = idx / 20, k = idx % 20;
      Wt[k][oc] = Wy[(size_t)oc * CIN + c0 + k];
    }
    __syncthreads();
#pragma unroll
    for (int k = 0; k < 20; ++k) {
      float4 av = *(const float4*)&At[k][pg * 4];
      float a[4] = {av.x, av.y, av.z, av.w};
      float b[13];
#pragma unroll
      for (int j = 0; j < 13; ++j) b[j] = Wt[k][og * 13 + j];
#pragma unroll
      for (int p = 0; p < 4; ++p)
#pragma unroll
        for (int j = 0; j < 13; ++j) acc[p][j] = fmaf(a[p], b[j], acc[p][j]);
    }
  }
#pragma unroll
  for (int p = 0; p < 4; ++p) {
    int l = l0 + pg * 4 + p;
    float* yrow = ye + ((size_t)n * L + l) * CIN;
#pragma unroll
    for (int j = 0; j < 13; ++j) {
      int oc = og * 13 + j;
      if (oc < CIN) yrow[oc] = acc[p][j];
    }
  }
}

// ---------------------------------------------------------------------------
// Stable counting sort of keys (u*100+label) -> 128 buckets (b = u*32+label).
// CHUNK = 512 elements, NCHUNK = 128 per batch.
// ---------------------------------------------------------------------------
__global__ __launch_bounds__(256) void k_hist(const int* __restrict__ sl,
                                              int* __restrict__ hist) {
  const int blk = blockIdx.x;           // n*128 + chunk
  const int n = blk >> 7, ch = blk & 127;
  __shared__ int h[128];
  if (threadIdx.x < 128) h[threadIdx.x] = 0;
  __syncthreads();
#pragma unroll
  for (int it = 0; it < 2; ++it) {
    int pos = ch * 512 + it * 256 + threadIdx.x;      // [0, 65536)
    int u = pos >> 14, l = pos & (L - 1);
    int lab = sl[((size_t)n * NS + u) * L + l] & 31;
    atomicAdd(&h[u * 32 + lab], 1);
  }
  __syncthreads();
  if (threadIdx.x < 128) hist[(blk << 7) + threadIdx.x] = h[threadIdx.x];
}

__global__ __launch_bounds__(128) void k_scan(const int* __restrict__ hist,
                                              int* __restrict__ offs) {
  const int n = blockIdx.x, b = threadIdx.x;
  __shared__ int tot[128];
  __shared__ int basebuf[128];
  int t = 0;
  for (int c = 0; c < 128; ++c) t += hist[(((size_t)n * 128 + c) << 7) + b];
  tot[b] = t;
  __syncthreads();
  if (b == 0) {
    int run = 0;
    for (int i = 0; i < 128; ++i) { basebuf[i] = run; run += tot[i]; }
  }
  __syncthreads();
  int run = basebuf[b];
  for (int c = 0; c < 128; ++c) {
    offs[(((size_t)n * 128 + c) << 7) + b] = run;
    run += hist[(((size_t)n * 128 + c) << 7) + b];
  }
}

__global__ __launch_bounds__(512) void k_scatter(const int* __restrict__ sl,
                                                 const int* __restrict__ offs,
                                                 int* __restrict__ perm) {
  const int blk = blockIdx.x;
  const int n = blk >> 7, ch = blk & 127;
  const int tid = threadIdx.x, wv = tid >> 6, lane = tid & 63;
  __shared__ int wh[8][128];
  for (int idx = tid; idx < 1024; idx += 512) ((int*)wh)[idx] = 0;
  __syncthreads();
  const int pos = ch * 512 + tid;
  const int u = pos >> 14, l = pos & (L - 1);
  const int b = u * 32 + (sl[((size_t)n * NS + u) * L + l] & 31);
  atomicAdd(&wh[wv][b], 1);
  // stable within-wave rank among equal buckets
  int lr = 0;
  for (int s = 0; s < 64; ++s) {
    int ob = __shfl(b, s);
    lr += (s < lane && ob == b) ? 1 : 0;
  }
  __syncthreads();
  if (tid < 128) {                       // exclusive prefix across waves
    int run = 0;
#pragma unroll
    for (int w = 0; w < 8; ++w) { int v = wh[w][tid]; wh[w][tid] = run; run += v; }
  }
  __syncthreads();
  const int rank = offs[(blk << 7) + b] + wh[wv][b] + lr;
  perm[(size_t)n * (NS * L) + rank] = pos;
}

// ---------------------------------------------------------------------------
// Windowed attention. grid (256 k, 4 u, 2 n), block 512.
// LDS: Pt[192][66] | union{ Qst[50][68]+Kst[50][196] , Yt[64][228] } | misc
// ---------------------------------------------------------------------------
#define PT_P  66
#define QS_P  68
#define KS_P  196
#define YT_P  228

__global__ __launch_bounds__(512) void k_attn(const float* __restrict__ xe,
                                              const float* __restrict__ ye,
                                              const int* __restrict__ perm,
                                              float* __restrict__ attnO) {
  const int kcl = blockIdx.x;
  const int u   = blockIdx.y;
  const int n   = blockIdx.z;
  const int tid = threadIdx.x;

  __shared__ __align__(16) char smraw[112384];
  float* Pt   = (float*)smraw;                          // 50688 B
  float* Qst  = (float*)(smraw + 50688);                // 13600 B
  float* Kst  = (float*)(smraw + 50688 + 13600);        // 39200 B
  float* Yt   = (float*)(smraw + 50688);                // 58368 B (aliases Qst/Kst)
  int*   lidx = (int*)(smraw + 50688 + 58368);          // 768 B
  float* rmax = (float*)(smraw + 50688 + 58368 + 768);  // 256 B
  float* rsum = (float*)(smraw + 50688 + 58368 + 1024); // 256 B
  float* red  = (float*)(smraw + 50688 + 58368 + 1280); // 2048 B

  if (tid < NKEY) {
    int kj = tid < 64 ? kcl
           : (tid < 128 ? ((kcl + KCL - 1) & (KCL - 1)) : ((kcl + 1) & (KCL - 1)));
    int p = (u << 14) + (kj << 6) + (tid & 63);
    lidx[tid] = perm[(size_t)n * (NS * L) + p] & (L - 1);
  }
  __syncthreads();

  // gather x rows, store transposed
  for (int idx = tid; idx < NKEY * CE; idx += 512) {
    int j = idx / CE, c = idx % CE;
    float v = xe[((size_t)n * L + lidx[j]) * CE + c];
    Kst[c * KS_P + j] = v;
    if (j < WIN) Qst[c * QS_P + j] = v;
  }
  __syncthreads();

  // L2-normalize key rows (columns of Kst)
  if (tid < NKEY) {
    float s = 0.f;
#pragma unroll
    for (int c = 0; c < CE; ++c) { float v = Kst[c * KS_P + tid]; s += v * v; }
    float inv = 1.f / fmaxf(sqrtf(s), 5e-5f);
#pragma unroll
    for (int c = 0; c < CE; ++c) Kst[c * KS_P + tid] *= inv;
  }
  __syncthreads();

  // S = Q * Kn^T  (64 x 192), stored transposed Pt[j][i]
  {
    const int ig = tid >> 5, jg = tid & 31;
    const int i0 = ig * 4, j0 = jg * 6;
    float s[4][6];
#pragma unroll
    for (int a = 0; a < 4; ++a)
#pragma unroll
      for (int b = 0; b < 6; ++b) s[a][b] = 0.f;
    for (int c = 0; c < CE; ++c) {
      float4 qv = *(const float4*)&Qst[c * QS_P + i0];
      float q[4] = {qv.x, qv.y, qv.z, qv.w};
      float kv[6];
#pragma unroll
      for (int b = 0; b < 6; ++b) kv[b] = Kst[c * KS_P + j0 + b];
#pragma unroll
      for (int a = 0; a < 4; ++a)
#pragma unroll
        for (int b = 0; b < 6; ++b) s[a][b] = fmaf(q[a], kv[b], s[a][b]);
    }
#pragma unroll
    for (int b = 0; b < 6; ++b)
#pragma unroll
      for (int a = 0; a < 4; ++a) Pt[(j0 + b) * PT_P + (i0 + a)] = s[a][b];
  }
  __syncthreads();

  // softmax over the 192 keys per query row
  {
    const int i = tid >> 3, q = tid & 7;
    float m = -1e30f;
#pragma unroll
    for (int jj = 0; jj < 24; ++jj) m = fmaxf(m, Pt[(q * 24 + jj) * PT_P + i]);
    red[i * 8 + q] = m;
    __syncthreads();
    if (q == 0) {
      float mm = red[i * 8];
#pragma unroll
      for (int t = 1; t < 8; ++t) mm = fmaxf(mm, red[i * 8 + t]);
      rmax[i] = mm;
    }
    __syncthreads();
    float mm = rmax[i];
    float ss = 0.f;
#pragma unroll
    for (int jj = 0; jj < 24; ++jj) {
      float v = expf(Pt[(q * 24 + jj) * PT_P + i] - mm);
      Pt[(q * 24 + jj) * PT_P + i] = v;
      ss += v;
    }
    red[i * 8 + q] = ss;
    __syncthreads();
    if (q == 0) {
      float s2 = 0.f;
#pragma unroll
      for (int t = 0; t < 8; ++t) s2 += red[i * 8 + t];
      rsum[i] = 1.f / s2;
    }
    __syncthreads();
    float inv = rsum[i];
#pragma unroll
    for (int jj = 0; jj < 24; ++jj) Pt[(q * 24 + jj) * PT_P + i] *= inv;
  }

  // O = P @ Y  (64 x 200), Y streamed in 3 tiles of 64 rows
  const int i = tid & 63, q = tid >> 6;   // e0 = q*28
  float acc[28];
#pragma unroll
  for (int e = 0; e < 28; ++e) acc[e] = 0.f;

  for (int T = 0; T < 3; ++T) {
    __syncthreads();                       // previous tile fully consumed
    for (int idx = tid; idx < 64 * 57; idx += 512) {
      int jj = idx / 57, f = idx % 57;
      float4 v = make_float4(0.f, 0.f, 0.f, 0.f);
      if (f < 50)
        v = *(const float4*)&ye[((size_t)n * L + lidx[T * 64 + jj]) * CIN + f * 4];
      *(float4*)&Yt[jj * YT_P + f * 4] = v;
    }
    __syncthreads();
#pragma unroll 4
    for (int jj = 0; jj < 64; ++jj) {
      float p = Pt[(T * 64 + jj) * PT_P + i];
      const float* yrow = &Yt[jj * YT_P + q * 28];
#pragma unroll
      for (int f = 0; f < 7; ++f) {
        float4 yv = *(const float4*)&yrow[f * 4];
        acc[f * 4 + 0] = fmaf(p, yv.x, acc[f * 4 + 0]);
        acc[f * 4 + 1] = fmaf(p, yv.y, acc[f * 4 + 1]);
        acc[f * 4 + 2] = fmaf(p, yv.z, acc[f * 4 + 2]);
        acc[f * 4 + 3] = fmaf(p, yv.w, acc[f * 4 + 3]);
      }
    }
  }

  // scatter to attnO[n][u][l][e]  (this IS the unsort)
  {
    const int l  = lidx[i];
    const int e0 = q * 28;
    float* orow = attnO + (((size_t)(n * NS + u) * L) + l) * CIN + e0;
    const int nf = (e0 + 28 <= CIN) ? 7 : (CIN - e0) / 4;   // q==7 -> 1
#pragma unroll
    for (int f = 0; f < 7; ++f)
      if (f < nf)
        *(float4*)&orow[f * 4] =
            make_float4(acc[f * 4], acc[f * 4 + 1], acc[f * 4 + 2], acc[f * 4 + 3]);
  }
}

// ---------------------------------------------------------------------------
// 1x1 Wout (K=800) + bias + residual -> out (N, 200, L). grid (256, N), block 256
// ---------------------------------------------------------------------------
__global__ __launch_bounds__(256) void k_wout(const float* __restrict__ attnO,
                                              const float* __restrict__ Wo,
                                              const float* __restrict__ bo,
                                              const float* __restrict__ in,
                                              float* __restrict__ out) {
  const int n  = blockIdx.y;
  const int l0 = blockIdx.x * 64;
  __shared__ __align__(16) char sm[44160];
  float* At = (float*)sm;            // [40][68]  10880 B
  float* Wt = (float*)(sm + 10880);  // [40][208] 33280 B
  const int pg = threadIdx.x >> 4, og = threadIdx.x & 15;
  const int tid = threadIdx.x;

  float acc[4][13];
#pragma unroll
  for (int p = 0; p < 4; ++p)
#pragma unroll
    for (int j = 0; j < 13; ++j) acc[p][j] = 0.f;

  for (int idx = tid; idx < 40 * 8; idx += 256)
    Wt[(idx >> 3) * 208 + 200 + (idx & 7)] = 0.f;

  for (int c0 = 0; c0 < 800; c0 += 40) {
    const int u = c0 / 200, e0 = c0 % 200;
    __syncthreads();
    for (int idx = tid; idx < 64 * 40; idx += 256) {
      int p = idx / 40, kk = idx % 40;
      At[kk * 68 + p] = attnO[(((size_t)(n * NS + u) * L) + l0 + p) * CIN + e0 + kk];
    }
    for (int idx = tid; idx < 200 * 40; idx += 256) {
      int oc = idx / 40, kk = idx % 40;
      Wt[kk * 208 + oc] = Wo[(size_t)oc * 800 + c0 + kk];
    }
    __syncthreads();
#pragma unroll 8
    for (int kk = 0; kk < 40; ++kk) {
      float4 av = *(const float4*)&At[kk * 68 + pg * 4];
      float a[4] = {av.x, av.y, av.z, av.w};
      float b[13];
#pragma unroll
      for (int j = 0; j < 13; ++j) b[j] = Wt[kk * 208 + og * 13 + j];
#pragma unroll
      for (int p = 0; p < 4; ++p)
#pragma unroll
        for (int j = 0; j < 13; ++j) acc[p][j] = fmaf(a[p], b[j], acc[p][j]);
    }
  }
  __syncthreads();

  // staged epilogue for coalesced stores
  float* Ot = (float*)sm;            // [104][64]
  for (int r = 0; r < 2; ++r) {
    const int ocb = r * 104;
    const int width = (r == 0) ? 104 : 96;
#pragma unroll
    for (int p = 0; p < 4; ++p)
#pragma unroll
      for (int j = 0; j < 13; ++j) {
        int oc = og * 13 + j;
        if (oc >= ocb && oc < ocb + width)
          Ot[(oc - ocb) * 64 + pg * 4 + p] = acc[p][j];
      }
    __syncthreads();
    for (int idx = tid; idx < width * 64; idx += 256) {
      int oc2 = idx >> 6, p = idx & 63;
      size_t o = ((size_t)n * CIN + ocb + oc2) * L + l0 + p;
      out[o] = Ot[oc2 * 64 + p] + bo[ocb + oc2] + in[o];
    }
    __syncthreads();
  }
}

// ---------------------------------------------------------------------------
extern "C" void kernel_launch(void* const* d_in, const int* in_sizes, int n_in,
                              void* d_out, int out_size, void* d_ws, size_t ws_size,
                              hipStream_t stream) {
  const float* in = (const float*)d_in[0];
  const int*   sl = (const int*)d_in[1];
  const float* Wx = (const float*)d_in[2];
  const float* Wy = (const float*)d_in[3];
  const float* Wo = (const float*)d_in[4];
  const float* bo = (const float*)d_in[5];
  float* out = (float*)d_out;

  // workspace layout (needs ~138.3 MB)
  float* xe   = (float*)d_ws;                           // 2*16384*50
  float* ye   = xe + (size_t)2 * L * CE;                // 2*16384*200
  float* attn = ye + (size_t)2 * L * CIN;               // 2*4*16384*200
  int*   perm = (int*)(attn + (size_t)2 * NS * L * CIN);
  int*   hist = perm + (size_t)2 * NS * L;
  int*   offs = hist + (size_t)2 * 128 * 128;

  k_conv3  <<<dim3(2, 64, 2),  256, 0, stream>>>(in, Wx, xe);
  k_wy     <<<dim3(256, 2),    256, 0, stream>>>(in, Wy, ye);
  k_hist   <<<256,             256, 0, stream>>>(sl, hist);
  k_scan   <<<2,               128, 0, stream>>>(hist, offs);
  k_scatter<<<256,             512, 0, stream>>>(sl, offs, perm);
  k_attn   <<<dim3(256, 4, 2), 512, 0, stream>>>(xe, ye, perm, attn);
  k_wout   <<<dim3(256, 2),    256, 0, stream>>>(attn, Wo, bo, in, out);
}

// Round 4
// 1206.806 us; speedup vs baseline: 1.1145x; 1.1145x over previous
//
#include <hip/hip_runtime.h>
#include <hip/hip_bf16.h>
#include <math.h>

#define L      16384
#define CIN    200
#define CE     50
#define NS     4
#define KCL    256
#define WIN    64
#define NKEY   192

// ---------------------------------------------------------------------------
// conv3x3 reflect-pad -> x_embed (N, L, 50)
// grid (5 oc-groups of 10, 64 tiles, N), block 256 (16x16 pixel tile).
// Weights read via wave-uniform scalar loads (s_load) -> no LDS for weights.
// 4 input channels staged per iteration, register-prefetched (2 barriers/4ic).
// ---------------------------------------------------------------------------
__global__ __launch_bounds__(256) void k_conv3(const float* __restrict__ in,
                                               const float* __restrict__ Wx,
                                               float* __restrict__ xe) {
  const int ocg  = blockIdx.x;          // 0..4
  const int tile = blockIdx.y;          // 0..63
  const int n    = blockIdx.z;
  const int th = tile >> 3, tw = tile & 7;
  const int ty = threadIdx.x >> 4, tx = threadIdx.x & 15;
  const int oc0 = ocg * 10;
  const int tid = threadIdx.x;

  __shared__ __align__(16) float patch[4 * 18 * 20];   // 5.6 KB

  const float* inN = in + (size_t)n * CIN * L;
  const float* wB  = Wx + (size_t)oc0 * CIN * 9;

  // stage-invariant load pattern: 4*18*18 = 1296 halo elements
  int goff[6], loff[6];
#pragma unroll
  for (int j = 0; j < 6; ++j) {
    int idx = tid + j * 256;
    if (idx < 1296) {
      int ic = idx / 324, rem = idx % 324;
      int r = rem / 18, c = rem % 18;
      int gh = th * 16 + r - 1, gw = tw * 16 + c - 1;
      gh = gh < 0 ? -gh : (gh > 127 ? 254 - gh : gh);
      gw = gw < 0 ? -gw : (gw > 127 ? 254 - gw : gw);
      goff[j] = ic * L + gh * 128 + gw;
      loff[j] = ic * 360 + r * 20 + c;
    } else {
      goff[j] = -1;
      loff[j] = 0;
    }
  }

  float acc[10];
#pragma unroll
  for (int o = 0; o < 10; ++o) acc[o] = 0.f;

  float pf[6];
#pragma unroll
  for (int j = 0; j < 6; ++j) pf[j] = (goff[j] >= 0) ? inN[goff[j]] : 0.f;

  for (int s = 0; s < 50; ++s) {
    __syncthreads();                     // previous stage's LDS reads done
#pragma unroll
    for (int j = 0; j < 6; ++j)
      if (goff[j] >= 0) patch[loff[j]] = pf[j];
    __syncthreads();
    if (s < 49) {                        // prefetch next stage (overlaps compute)
      const float* src = inN + (size_t)(s + 1) * 4 * L;
#pragma unroll
      for (int j = 0; j < 6; ++j) pf[j] = (goff[j] >= 0) ? src[goff[j]] : 0.f;
    }

    float p[4][9];
#pragma unroll
    for (int icc = 0; icc < 4; ++icc) {
      const float* pb = &patch[icc * 360 + ty * 20 + tx];
#pragma unroll
      for (int dr = 0; dr < 3; ++dr)
#pragma unroll
        for (int dc = 0; dc < 3; ++dc)
          p[icc][dr * 3 + dc] = pb[dr * 20 + dc];
    }
    const float* wS = wB + (size_t)(4 * s) * 9;
#pragma unroll
    for (int o = 0; o < 10; ++o) {
      const float* wO = wS + (size_t)o * CIN * 9;   // uniform -> s_load
#pragma unroll
      for (int icc = 0; icc < 4; ++icc)
#pragma unroll
        for (int q = 0; q < 9; ++q)
          acc[o] = fmaf(p[icc][q], wO[icc * 9 + q], acc[o]);
    }
  }

  const int l = (th * 16 + ty) * 128 + (tw * 16 + tx);
  float* xrow = xe + ((size_t)n * L + l) * CE + oc0;
#pragma unroll
  for (int o = 0; o < 5; ++o)
    *(float2*)&xrow[o * 2] = make_float2(acc[o * 2], acc[o * 2 + 1]);
}

// ---------------------------------------------------------------------------
// 1x1 Wy -> y_embed (N, L, 200).  grid (256 l-tiles, N), block 256
// ---------------------------------------------------------------------------
__global__ __launch_bounds__(256) void k_wy(const float* __restrict__ in,
                                            const float* __restrict__ Wy,
                                            float* __restrict__ ye) {
  const int n  = blockIdx.y;
  const int l0 = blockIdx.x * 64;
  __shared__ __align__(16) float At[20][64];
  __shared__ __align__(16) float Wt[20][208];
  const int pg = threadIdx.x >> 4, og = threadIdx.x & 15;

  float acc[4][13];
#pragma unroll
  for (int p = 0; p < 4; ++p)
#pragma unroll
    for (int j = 0; j < 13; ++j) acc[p][j] = 0.f;

  // zero the oc padding columns once
  for (int idx = threadIdx.x; idx < 20 * 8; idx += 256)
    Wt[idx >> 3][200 + (idx & 7)] = 0.f;

  const float* inN = in + (size_t)n * CIN * L + l0;
  for (int c0 = 0; c0 < CIN; c0 += 20) {
    __syncthreads();
    for (int idx = threadIdx.x; idx < 20 * 64; idx += 256) {
      int k = idx >> 6, p = idx & 63;
      At[k][p] = inN[(size_t)(c0 + k) * L + p];
    }
    for (int idx = threadIdx.x; idx < 200 * 20; idx += 256) {
      int oc = idx / 20, k = idx % 20;
      Wt[k][oc] = Wy[(size_t)oc * CIN + c0 + k];
    }
    __syncthreads();
#pragma unroll
    for (int k = 0; k < 20; ++k) {
      float4 av = *(const float4*)&At[k][pg * 4];
      float a[4] = {av.x, av.y, av.z, av.w};
      float b[13];
#pragma unroll
      for (int j = 0; j < 13; ++j) b[j] = Wt[k][og * 13 + j];
#pragma unroll
      for (int p = 0; p < 4; ++p)
#pragma unroll
        for (int j = 0; j < 13; ++j) acc[p][j] = fmaf(a[p], b[j], acc[p][j]);
    }
  }
#pragma unroll
  for (int p = 0; p < 4; ++p) {
    int l = l0 + pg * 4 + p;
    float* yrow = ye + ((size_t)n * L + l) * CIN;
#pragma unroll
    for (int j = 0; j < 13; ++j) {
      int oc = og * 13 + j;
      if (oc < CIN) yrow[oc] = acc[p][j];
    }
  }
}

// ---------------------------------------------------------------------------
// Stable counting sort of keys (u*100+label) -> 128 buckets (b = u*32+label).
// ---------------------------------------------------------------------------
__global__ __launch_bounds__(256) void k_hist(const int* __restrict__ sl,
                                              int* __restrict__ hist) {
  const int blk = blockIdx.x;           // n*128 + chunk
  const int n = blk >> 7, ch = blk & 127;
  __shared__ int h[128];
  if (threadIdx.x < 128) h[threadIdx.x] = 0;
  __syncthreads();
#pragma unroll
  for (int it = 0; it < 2; ++it) {
    int pos = ch * 512 + it * 256 + threadIdx.x;      // [0, 65536)
    int u = pos >> 14, l = pos & (L - 1);
    int lab = sl[((size_t)n * NS + u) * L + l] & 31;
    atomicAdd(&h[u * 32 + lab], 1);
  }
  __syncthreads();
  if (threadIdx.x < 128) hist[(blk << 7) + threadIdx.x] = h[threadIdx.x];
}

__global__ __launch_bounds__(128) void k_scan(const int* __restrict__ hist,
                                              int* __restrict__ offs) {
  const int n = blockIdx.x, b = threadIdx.x;
  __shared__ int tot[128];
  __shared__ int basebuf[128];
  int t = 0;
  for (int c = 0; c < 128; ++c) t += hist[(((size_t)n * 128 + c) << 7) + b];
  tot[b] = t;
  __syncthreads();
  if (b == 0) {
    int run = 0;
    for (int i = 0; i < 128; ++i) { basebuf[i] = run; run += tot[i]; }
  }
  __syncthreads();
  int run = basebuf[b];
  for (int c = 0; c < 128; ++c) {
    offs[(((size_t)n * 128 + c) << 7) + b] = run;
    run += hist[(((size_t)n * 128 + c) << 7) + b];
  }
}

__global__ __launch_bounds__(512) void k_scatter(const int* __restrict__ sl,
                                                 const int* __restrict__ offs,
                                                 int* __restrict__ perm) {
  const int blk = blockIdx.x;
  const int n = blk >> 7, ch = blk & 127;
  const int tid = threadIdx.x, wv = tid >> 6, lane = tid & 63;
  __shared__ int wh[8][128];
  for (int idx = tid; idx < 1024; idx += 512) ((int*)wh)[idx] = 0;
  __syncthreads();
  const int pos = ch * 512 + tid;
  const int u = pos >> 14, l = pos & (L - 1);
  const int b = u * 32 + (sl[((size_t)n * NS + u) * L + l] & 31);
  atomicAdd(&wh[wv][b], 1);
  // stable within-wave rank among equal buckets
  int lr = 0;
  for (int s = 0; s < 64; ++s) {
    int ob = __shfl(b, s);
    lr += (s < lane && ob == b) ? 1 : 0;
  }
  __syncthreads();
  if (tid < 128) {                       // exclusive prefix across waves
    int run = 0;
#pragma unroll
    for (int w = 0; w < 8; ++w) { int v = wh[w][tid]; wh[w][tid] = run; run += v; }
  }
  __syncthreads();
  const int rank = offs[(blk << 7) + b] + wh[wv][b] + lr;
  perm[(size_t)n * (NS * L) + rank] = pos;
}

// ---------------------------------------------------------------------------
// Windowed attention. grid (256 k, 4 u, 2 n), block 512.
// ---------------------------------------------------------------------------
#define PT_P  66
#define QS_P  68
#define KS_P  196
#define YT_P  228

__global__ __launch_bounds__(512) void k_attn(const float* __restrict__ xe,
                                              const float* __restrict__ ye,
                                              const int* __restrict__ perm,
                                              float* __restrict__ attnO) {
  const int kcl = blockIdx.x;
  const int u   = blockIdx.y;
  const int n   = blockIdx.z;
  const int tid = threadIdx.x;

  __shared__ __align__(16) char smraw[112384];
  float* Pt   = (float*)smraw;                          // 50688 B
  float* Qst  = (float*)(smraw + 50688);                // 13600 B
  float* Kst  = (float*)(smraw + 50688 + 13600);        // 39200 B
  float* Yt   = (float*)(smraw + 50688);                // 58368 B (aliases Qst/Kst)
  int*   lidx = (int*)(smraw + 50688 + 58368);          // 768 B
  float* rmax = (float*)(smraw + 50688 + 58368 + 768);  // 256 B
  float* rsum = (float*)(smraw + 50688 + 58368 + 1024); // 256 B
  float* red  = (float*)(smraw + 50688 + 58368 + 1280); // 2048 B

  if (tid < NKEY) {
    int kj = tid < 64 ? kcl
           : (tid < 128 ? ((kcl + KCL - 1) & (KCL - 1)) : ((kcl + 1) & (KCL - 1)));
    int p = (u << 14) + (kj << 6) + (tid & 63);
    lidx[tid] = perm[(size_t)n * (NS * L) + p] & (L - 1);
  }
  __syncthreads();

  // gather x rows, store transposed
  for (int idx = tid; idx < NKEY * CE; idx += 512) {
    int j = idx / CE, c = idx % CE;
    float v = xe[((size_t)n * L + lidx[j]) * CE + c];
    Kst[c * KS_P + j] = v;
    if (j < WIN) Qst[c * QS_P + j] = v;
  }
  __syncthreads();

  // L2-normalize key rows (columns of Kst)
  if (tid < NKEY) {
    float s = 0.f;
#pragma unroll
    for (int c = 0; c < CE; ++c) { float v = Kst[c * KS_P + tid]; s += v * v; }
    float inv = 1.f / fmaxf(sqrtf(s), 5e-5f);
#pragma unroll
    for (int c = 0; c < CE; ++c) Kst[c * KS_P + tid] *= inv;
  }
  __syncthreads();

  // S = Q * Kn^T  (64 x 192), stored transposed Pt[j][i]
  {
    const int ig = tid >> 5, jg = tid & 31;
    const int i0 = ig * 4, j0 = jg * 6;
    float s[4][6];
#pragma unroll
    for (int a = 0; a < 4; ++a)
#pragma unroll
      for (int b = 0; b < 6; ++b) s[a][b] = 0.f;
    for (int c = 0; c < CE; ++c) {
      float4 qv = *(const float4*)&Qst[c * QS_P + i0];
      float q[4] = {qv.x, qv.y, qv.z, qv.w};
      float kv[6];
#pragma unroll
      for (int b = 0; b < 6; ++b) kv[b] = Kst[c * KS_P + j0 + b];
#pragma unroll
      for (int a = 0; a < 4; ++a)
#pragma unroll
        for (int b = 0; b < 6; ++b) s[a][b] = fmaf(q[a], kv[b], s[a][b]);
    }
#pragma unroll
    for (int b = 0; b < 6; ++b)
#pragma unroll
      for (int a = 0; a < 4; ++a) Pt[(j0 + b) * PT_P + (i0 + a)] = s[a][b];
  }
  __syncthreads();

  // softmax over the 192 keys per query row
  {
    const int i = tid >> 3, q = tid & 7;
    float m = -1e30f;
#pragma unroll
    for (int jj = 0; jj < 24; ++jj) m = fmaxf(m, Pt[(q * 24 + jj) * PT_P + i]);
    red[i * 8 + q] = m;
    __syncthreads();
    if (q == 0) {
      float mm = red[i * 8];
#pragma unroll
      for (int t = 1; t < 8; ++t) mm = fmaxf(mm, red[i * 8 + t]);
      rmax[i] = mm;
    }
    __syncthreads();
    float mm = rmax[i];
    float ss = 0.f;
#pragma unroll
    for (int jj = 0; jj < 24; ++jj) {
      float v = expf(Pt[(q * 24 + jj) * PT_P + i] - mm);
      Pt[(q * 24 + jj) * PT_P + i] = v;
      ss += v;
    }
    red[i * 8 + q] = ss;
    __syncthreads();
    if (q == 0) {
      float s2 = 0.f;
#pragma unroll
      for (int t = 0; t < 8; ++t) s2 += red[i * 8 + t];
      rsum[i] = 1.f / s2;
    }
    __syncthreads();
    float inv = rsum[i];
#pragma unroll
    for (int jj = 0; jj < 24; ++jj) Pt[(q * 24 + jj) * PT_P + i] *= inv;
  }

  // O = P @ Y  (64 x 200), Y streamed in 3 tiles of 64 rows
  const int i = tid & 63, q = tid >> 6;   // e0 = q*28
  float acc[28];
#pragma unroll
  for (int e = 0; e < 28; ++e) acc[e] = 0.f;

  for (int T = 0; T < 3; ++T) {
    __syncthreads();                       // previous tile fully consumed
    for (int idx = tid; idx < 64 * 57; idx += 512) {
      int jj = idx / 57, f = idx % 57;
      float4 v = make_float4(0.f, 0.f, 0.f, 0.f);
      if (f < 50)
        v = *(const float4*)&ye[((size_t)n * L + lidx[T * 64 + jj]) * CIN + f * 4];
      *(float4*)&Yt[jj * YT_P + f * 4] = v;
    }
    __syncthreads();
#pragma unroll 4
    for (int jj = 0; jj < 64; ++jj) {
      float p = Pt[(T * 64 + jj) * PT_P + i];
      const float* yrow = &Yt[jj * YT_P + q * 28];
#pragma unroll
      for (int f = 0; f < 7; ++f) {
        float4 yv = *(const float4*)&yrow[f * 4];
        acc[f * 4 + 0] = fmaf(p, yv.x, acc[f * 4 + 0]);
        acc[f * 4 + 1] = fmaf(p, yv.y, acc[f * 4 + 1]);
        acc[f * 4 + 2] = fmaf(p, yv.z, acc[f * 4 + 2]);
        acc[f * 4 + 3] = fmaf(p, yv.w, acc[f * 4 + 3]);
      }
    }
  }

  // scatter to attnO[n][u][l][e]  (this IS the unsort)
  {
    const int l  = lidx[i];
    const int e0 = q * 28;
    float* orow = attnO + (((size_t)(n * NS + u) * L) + l) * CIN + e0;
    const int nf = (e0 + 28 <= CIN) ? 7 : (CIN - e0) / 4;   // q==7 -> 1
#pragma unroll
    for (int f = 0; f < 7; ++f)
      if (f < nf)
        *(float4*)&orow[f * 4] =
            make_float4(acc[f * 4], acc[f * 4 + 1], acc[f * 4 + 2], acc[f * 4 + 3]);
  }
}

// ---------------------------------------------------------------------------
// 1x1 Wout (K=800) + bias + residual -> out (N, 200, L). grid (256, N), block 256
// ---------------------------------------------------------------------------
__global__ __launch_bounds__(256) void k_wout(const float* __restrict__ attnO,
                                              const float* __restrict__ Wo,
                                              const float* __restrict__ bo,
                                              const float* __restrict__ in,
                                              float* __restrict__ out) {
  const int n  = blockIdx.y;
  const int l0 = blockIdx.x * 64;
  __shared__ __align__(16) char sm[44160];
  float* At = (float*)sm;            // [40][68]  10880 B
  float* Wt = (float*)(sm + 10880);  // [40][208] 33280 B
  const int pg = threadIdx.x >> 4, og = threadIdx.x & 15;
  const int tid = threadIdx.x;

  float acc[4][13];
#pragma unroll
  for (int p = 0; p < 4; ++p)
#pragma unroll
    for (int j = 0; j < 13; ++j) acc[p][j] = 0.f;

  for (int idx = tid; idx < 40 * 8; idx += 256)
    Wt[(idx >> 3) * 208 + 200 + (idx & 7)] = 0.f;

  for (int c0 = 0; c0 < 800; c0 += 40) {
    const int u = c0 / 200, e0 = c0 % 200;
    __syncthreads();
    for (int idx = tid; idx < 64 * 40; idx += 256) {
      int p = idx / 40, kk = idx % 40;
      At[kk * 68 + p] = attnO[(((size_t)(n * NS + u) * L) + l0 + p) * CIN + e0 + kk];
    }
    for (int idx = tid; idx < 200 * 40; idx += 256) {
      int oc = idx / 40, kk = idx % 40;
      Wt[kk * 208 + oc] = Wo[(size_t)oc * 800 + c0 + kk];
    }
    __syncthreads();
#pragma unroll 8
    for (int kk = 0; kk < 40; ++kk) {
      float4 av = *(const float4*)&At[kk * 68 + pg * 4];
      float a[4] = {av.x, av.y, av.z, av.w};
      float b[13];
#pragma unroll
      for (int j = 0; j < 13; ++j) b[j] = Wt[kk * 208 + og * 13 + j];
#pragma unroll
      for (int p = 0; p < 4; ++p)
#pragma unroll
        for (int j = 0; j < 13; ++j) acc[p][j] = fmaf(a[p], b[j], acc[p][j]);
    }
  }
  __syncthreads();

  // staged epilogue for coalesced stores
  float* Ot = (float*)sm;            // [104][64]
  for (int r = 0; r < 2; ++r) {
    const int ocb = r * 104;
    const int width = (r == 0) ? 104 : 96;
#pragma unroll
    for (int p = 0; p < 4; ++p)
#pragma unroll
      for (int j = 0; j < 13; ++j) {
        int oc = og * 13 + j;
        if (oc >= ocb && oc < ocb + width)
          Ot[(oc - ocb) * 64 + pg * 4 + p] = acc[p][j];
      }
    __syncthreads();
    for (int idx = tid; idx < width * 64; idx += 256) {
      int oc2 = idx >> 6, p = idx & 63;
      size_t o = ((size_t)n * CIN + ocb + oc2) * L + l0 + p;
      out[o] = Ot[oc2 * 64 + p] + bo[ocb + oc2] + in[o];
    }
    __syncthreads();
  }
}

// ---------------------------------------------------------------------------
extern "C" void kernel_launch(void* const* d_in, const int* in_sizes, int n_in,
                              void* d_out, int out_size, void* d_ws, size_t ws_size,
                              hipStream_t stream) {
  const float* in = (const float*)d_in[0];
  const int*   sl = (const int*)d_in[1];
  const float* Wx = (const float*)d_in[2];
  const float* Wy = (const float*)d_in[3];
  const float* Wo = (const float*)d_in[4];
  const float* bo = (const float*)d_in[5];
  float* out = (float*)d_out;

  // workspace layout (needs ~138.3 MB)
  float* xe   = (float*)d_ws;                           // 2*16384*50
  float* ye   = xe + (size_t)2 * L * CE;                // 2*16384*200
  float* attn = ye + (size_t)2 * L * CIN;               // 2*4*16384*200
  int*   perm = (int*)(attn + (size_t)2 * NS * L * CIN);
  int*   hist = perm + (size_t)2 * NS * L;
  int*   offs = hist + (size_t)2 * 128 * 128;

  k_conv3  <<<dim3(5, 64, 2),  256, 0, stream>>>(in, Wx, xe);
  k_wy     <<<dim3(256, 2),    256, 0, stream>>>(in, Wy, ye);
  k_hist   <<<256,             256, 0, stream>>>(sl, hist);
  k_scan   <<<2,               128, 0, stream>>>(hist, offs);
  k_scatter<<<256,             512, 0, stream>>>(sl, offs, perm);
  k_attn   <<<dim3(256, 4, 2), 512, 0, stream>>>(xe, ye, perm, attn);
  k_wout   <<<dim3(256, 2),    256, 0, stream>>>(attn, Wo, bo, in, out);
}